// Round 9
// baseline (8359.653 us; speedup 1.0000x reference)
//
#include <hip/hip_runtime.h>
#include <stdint.h>

#define B_   32
#define NV_  512
#define NL_  256
#define D_   1024
#define H_   4096
#define KTOT 768
#define SCALE_ 0.03125f   // 1/sqrt(1024)

typedef __attribute__((ext_vector_type(8))) __bf16 bf8_t;
typedef __attribute__((ext_vector_type(4))) float f32x4;

__device__ __forceinline__ unsigned short f2bf(float f) {
    unsigned u = __float_as_uint(f);
    u += 0x7FFFu + ((u >> 16) & 1u);       // round-to-nearest-even
    return (unsigned short)(u >> 16);
}
__device__ __forceinline__ unsigned pk2(float lo, float hi) {
    return (unsigned)f2bf(lo) | ((unsigned)f2bf(hi) << 16);
}

// async global->LDS, 16B per lane. LDS dest = wave-uniform base + lane*16.
__device__ __forceinline__ void gl_lds16(const void* g, const void* lds) {
    __builtin_amdgcn_global_load_lds(
        (const __attribute__((address_space(1))) unsigned int*)(uintptr_t)g,
        (__attribute__((address_space(3))) unsigned int*)(unsigned)(uintptr_t)lds,
        16, 0, 0);
}

#define SBAR() asm volatile("s_barrier" ::: "memory")
#define VMC4() asm volatile("s_waitcnt vmcnt(4)" ::: "memory")
#define VMC0() asm volatile("s_waitcnt vmcnt(0)" ::: "memory")
#define LGK0() asm volatile("s_waitcnt lgkmcnt(0)" ::: "memory")

// ===========================================================================
// 256x256 bf16 MFMA GEMM — round-9: BK=32, 64 KiB LDS, 2 blocks/CU (TLP).
// 512 thr = 8 waves (2Mx4N); per wave 128x64 out; double-buffered.
//
// LDS region per operand per buf = 16 KiB = [128 R][128 B]: logical (row r,
// k-byte c2) stored at R=r&127: byte = R*128 + (((r>>7)*64 + c2hi*16) ^
// ((R&7)<<4)) + c2lo  (bit6 = row-half select folded into the XOR swizzle;
// bijective per 128B line; read pattern spreads 8 rows over 32 banks).
// Staging (rule #21, both-sides): thread tid covers linear bytes tid*16
// (+8192); inverse map gives src row (tid>>3) + ((e>>2)&1)*128, k-off
// 8*(e&3) bf16, where e = (tid&7) ^ ((tid>>3)&7); chunk2 = src + 64*ld.
// Verified round-trip: (r=5,k=12) -> byte 712 -> stage tid44 -> read lane21.
//
// K-loop per tile t (2 barriers, 1 counted vmcnt, 1 lgkmcnt):
//   reads: 12 ds_read_b128 (aR[8], bR[4]) from buf_t
//   LGK0; SBAR;              <- all waves' reads of buf_t complete
//   STG(t+2) [4 loads];      <- overwrites buf_t
//   VMC4; SBAR;              <- drains tile t+1 (resident for next segment)
//   32 MFMA from registers (setprio-wrapped), overlapping t+2 loads
// With 2 independent blocks/CU the other block's MFMA fills our read/sync
// windows (anti-phase TLP) — the mechanism 1-block lockstep lacks.
// EPI: 0 relu(acc+bias)->bf16 ; 1 acc+bias->bf16 (+opt dual-store) ;
//      2 acc*scale -> f32 direct.
// ===========================================================================
template<int EPI>
__global__ __launch_bounds__(512, 4)
void gemm256(const unsigned short* __restrict__ Ab, long sAz, int lda,
             const unsigned short* __restrict__ Bb, long sBz, int ldb,
             const float* __restrict__ bias, float scale,
             void* __restrict__ Cp, unsigned short* __restrict__ C2p,
             long sCz, int ldc, int K,
             int nx, int ntile, int tpc)
{
    extern __shared__ unsigned char lds[];
    unsigned char* const ldsA = lds;            // buf*16384
    unsigned char* const ldsB = lds + 32768;    // buf*16384

    const int tid = threadIdx.x;
    const int w = tid >> 6, l = tid & 63;
    const int wr = w >> 2, wc = w & 3;          // 2 x 4 wave grid
    const int lrow = l & 15;
    const int kg = l >> 4;

    int t_, z;
    {
        const int bid = blockIdx.x;
        if (tpc > 0) { const int r = bid >> 3, c = bid & 7; z = r / tpc; t_ = c * tpc + r % tpc; }
        else         { z = bid / ntile; t_ = bid - z * ntile; }
    }
    const int n0 = (t_ % nx) * 256, m0 = (t_ / nx) * 256;

    const unsigned short* A  = Ab + (long)z * sAz;
    const unsigned short* Bg = Bb + (long)z * sBz;

    // staging source geometry (inverse-swizzled)
    const int e = (tid & 7) ^ ((tid >> 3) & 7);
    const int sxrow = (tid >> 3) + ((e >> 2) & 1) * 128;
    const int sxcol = (e & 3) * 8;                 // bf16 elements
    const int ntk = K >> 5;                        // # K-tiles (even: K mult of 64)

    // read column-byte offsets (constant per thread; row-swizzle pre-folded)
    const int csAx = ((l >> 4) * 16 + wr * 64) ^ ((l & 7) << 4);
    const int csBx = ((l >> 4) * 16 + (wc >> 1) * 64) ^ ((l & 7) << 4);

    const unsigned short* const spA = A  + (long)(m0 + sxrow) * lda + sxcol;
    const unsigned short* const spB = Bg + (long)(n0 + sxrow) * ldb + sxcol;
    const long stA = (long)64 * lda, stB = (long)64 * ldb;

    f32x4 acc[8][4];
#pragma unroll
    for (int i = 0; i < 8; ++i)
#pragma unroll
        for (int j = 0; j < 4; ++j) acc[i][j] = (f32x4){0.f, 0.f, 0.f, 0.f};

#define STG(tau) do {                                                         \
        const int buf_ = (tau) & 1;                                           \
        const int kt_ = ((tau) < ntk ? (tau) : ntk - 1);                      \
        const unsigned short* sA_ = spA + (long)kt_ * 32;                     \
        const unsigned short* sB_ = spB + (long)kt_ * 32;                     \
        unsigned char* dA_ = ldsA + buf_ * 16384 + w * 1024;                  \
        unsigned char* dB_ = ldsB + buf_ * 16384 + w * 1024;                  \
        gl_lds16(sA_, dA_); gl_lds16(sA_ + stA, dA_ + 8192);                  \
        gl_lds16(sB_, dB_); gl_lds16(sB_ + stB, dB_ + 8192);                  \
    } while (0)

    bf8_t aR[8], bR[4];

#define RDS(BUF)                                                              \
    _Pragma("unroll")                                                         \
    for (int mf = 0; mf < 8; ++mf)                                            \
        aR[mf] = *(const bf8_t*)(ldsA + (BUF) * 16384 +                       \
                                 (mf * 16 + lrow) * 128 + csAx);              \
    _Pragma("unroll")                                                         \
    for (int nf = 0; nf < 4; ++nf)                                            \
        bR[nf] = *(const bf8_t*)(ldsB + (BUF) * 16384 +                       \
                                 ((wc & 1) * 64 + nf * 16 + lrow) * 128 + csBx);

#define MFM()                                                                 \
    __builtin_amdgcn_s_setprio(1);                                            \
    _Pragma("unroll")                                                         \
    for (int mf = 0; mf < 8; ++mf)                                            \
    _Pragma("unroll")                                                         \
        for (int nf = 0; nf < 4; ++nf)                                        \
            acc[mf][nf] = __builtin_amdgcn_mfma_f32_16x16x32_bf16(            \
                aR[mf], bR[nf], acc[mf][nf], 0, 0, 0);                        \
    __builtin_amdgcn_s_setprio(0);

    // ---- prologue: stage tiles 0,1; tile0 resident ----
    STG(0); STG(1);
    VMC4();
    SBAR();

    for (int t = 0; t < ntk; t += 2) {
        // tile t (buf0)
        RDS(0)
        LGK0(); SBAR();
        STG(t + 2);
        VMC4(); SBAR();
        MFM()
        // tile t+1 (buf1)
        RDS(1)
        LGK0(); SBAR();
        STG(t + 3);
        VMC4(); SBAR();
        MFM()
    }
#undef MFM
#undef RDS
#undef STG

    VMC0();   // drain garbage tail stages
    SBAR();   // all waves drained -> LDS safe to repurpose

    if (EPI == 2) {
        float* C = (float*)Cp + (long)z * sCz;
#pragma unroll
        for (int mf = 0; mf < 8; ++mf)
#pragma unroll
            for (int nf = 0; nf < 4; ++nf)
#pragma unroll
                for (int r = 0; r < 4; ++r)
                    C[(long)(m0 + wr * 128 + mf * 16 + kg * 4 + r) * ldc +
                      (n0 + wc * 64 + nf * 16 + lrow)] = acc[mf][nf][r] * scale;
        return;
    }

    // ---- bf16 epilogue: per-wave LDS repack (8 KiB/wave), 4 passes ----
    unsigned short* C  = (unsigned short*)Cp + (long)z * sCz;
    unsigned short* C2 = C2p ? (C2p + (long)z * sCz) : nullptr;
    unsigned char* const scr = lds + w * 8192;

    float bv[4];
#pragma unroll
    for (int nf = 0; nf < 4; ++nf) bv[nf] = bias[n0 + wc * 64 + nf * 16 + lrow];

#pragma unroll
    for (int p = 0; p < 4; ++p) {
#pragma unroll
        for (int mfl = 0; mfl < 2; ++mfl)
#pragma unroll
            for (int nf = 0; nf < 4; ++nf)
#pragma unroll
                for (int r = 0; r < 4; ++r) {
                    float v = acc[2 * p + mfl][nf][r] + bv[nf];
                    if (EPI == 0) v = fmaxf(v, 0.f);
                    *(unsigned short*)(scr + (mfl * 16 + kg * 4 + r) * 136 +
                                       (nf * 16 + lrow) * 2) = f2bf(v);
                }
#pragma unroll
        for (int it = 0; it < 4; ++it) {
            const int rr = it * 8 + (l >> 3);
            const uint4 q = *(const uint4*)(scr + rr * 136 + (l & 7) * 16);
            const long off = (long)(m0 + wr * 128 + p * 32 + rr) * ldc +
                             (n0 + wc * 64 + (l & 7) * 8);
            *(uint4*)(C + off) = q;
            if (C2) *(uint4*)(C2 + off) = q;
        }
    }
}

// ===========================================================================
// attn + helpers (unchanged).
// ===========================================================================
__device__ __forceinline__ void supertile(int nx, int tpc, int& n0, int& m0, int& z)
{
    const int bid = blockIdx.x;
    const int r = bid >> 3, c = bid & 7;
    z = r / tpc;
    const int t = c * tpc + (r % tpc);
    n0 = (t % nx) * 128;
    m0 = (t / nx) * 128;
}

__global__ __launch_bounds__(256)
void col_stats(const float* __restrict__ A, float* __restrict__ Mst, float* __restrict__ RS)
{
    __shared__ float red[4][64];
    const int t = threadIdx.x;
    const int kk = t & 63, ng = t >> 6;
    const int k = blockIdx.x * 64 + kk;
    const int z = blockIdx.y;
    const float* base = A + (long)z * NV_ * KTOT + k;
    float m = -3.0e38f;
    for (int n = ng * 128; n < ng * 128 + 128; ++n) m = fmaxf(m, base[(long)n * KTOT]);
    red[ng][kk] = m;
    __syncthreads();
    m = fmaxf(fmaxf(red[0][kk], red[1][kk]), fmaxf(red[2][kk], red[3][kk]));
    float s = 0.f;
    for (int n = ng * 128; n < ng * 128 + 128; ++n) s += __expf(base[(long)n * KTOT] - m);
    __syncthreads();
    red[ng][kk] = s;
    __syncthreads();
    if (ng == 0) {
        s = red[0][kk] + red[1][kk] + red[2][kk] + red[3][kk];
        Mst[(long)z * KTOT + k] = m;
        RS[(long)z * KTOT + k]  = 1.f / s;
    }
}

__global__ __launch_bounds__(256)
void attn_mfma(const float* __restrict__ Ap, const unsigned short* __restrict__ KVt,
               const float* __restrict__ Mstp, const float* __restrict__ RSp,
               float* __restrict__ Cp, int nx, int tpc)
{
    __shared__ unsigned short As[128 * 32];
    __shared__ unsigned short Bs[128 * 32];

    const int tid = threadIdx.x;
    const int w = tid >> 6, l = tid & 63;
    const int wr = w >> 1, wc = w & 1;
    const int l15 = l & 15, kg = l >> 4;
    const int srow = l >> 2, scol = (l & 3) * 8;
    int n0, m0, z;
    supertile(nx, tpc, n0, m0, z);

    const float* A = Ap + (long)z * NV_ * KTOT;
    const unsigned short* Bg = KVt + (long)z * D_ * KTOT;
    const float* Mz = Mstp + (long)z * KTOT;
    const float* Rz = RSp  + (long)z * KTOT;
    float* C = Cp + (long)z * NV_ * D_;

    const int ar = tid >> 1;
    const int ah = (tid & 1) * 16;

    f32x4 acc[4][4];
#pragma unroll
    for (int m = 0; m < 4; ++m)
#pragma unroll
        for (int n = 0; n < 4; ++n) acc[m][n] = (f32x4){0.f, 0.f, 0.f, 0.f};

    for (int k0 = 0; k0 < KTOT; k0 += 32) {
#pragma unroll
        for (int i = 0; i < 2; ++i) {
            const int g = i * 4 + w;
            gl_lds16(Bg + (long)(n0 + g * 16 + srow) * KTOT + (k0 + scol), &Bs[g * 512]);
        }
        const float* arow = A + (long)(m0 + ar) * KTOT + k0 + ah;
        const float4 x0 = *(const float4*)(arow);
        const float4 x1 = *(const float4*)(arow + 4);
        const float4 x2 = *(const float4*)(arow + 8);
        const float4 x3 = *(const float4*)(arow + 12);
        const float4 ma = *(const float4*)(Mz + k0 + ah);
        const float4 mb = *(const float4*)(Mz + k0 + ah + 4);
        const float4 mc = *(const float4*)(Mz + k0 + ah + 8);
        const float4 md = *(const float4*)(Mz + k0 + ah + 12);
        const float4 ra = *(const float4*)(Rz + k0 + ah);
        const float4 rb = *(const float4*)(Rz + k0 + ah + 4);
        const float4 rc = *(const float4*)(Rz + k0 + ah + 8);
        const float4 rd = *(const float4*)(Rz + k0 + ah + 12);
        const unsigned q0 = pk2(__expf(x0.x - ma.x) * ra.x, __expf(x0.y - ma.y) * ra.y);
        const unsigned q1 = pk2(__expf(x0.z - ma.z) * ra.z, __expf(x0.w - ma.w) * ra.w);
        const unsigned q2 = pk2(__expf(x1.x - mb.x) * rb.x, __expf(x1.y - mb.y) * rb.y);
        const unsigned q3 = pk2(__expf(x1.z - mb.z) * rb.z, __expf(x1.w - mb.w) * rb.w);
        const unsigned q4 = pk2(__expf(x2.x - mc.x) * rc.x, __expf(x2.y - mc.y) * rc.y);
        const unsigned q5 = pk2(__expf(x2.z - mc.z) * rc.z, __expf(x2.w - mc.w) * rc.w);
        const unsigned q6 = pk2(__expf(x3.x - md.x) * rd.x, __expf(x3.y - md.y) * rd.y);
        const unsigned q7 = pk2(__expf(x3.z - md.z) * rd.z, __expf(x3.w - md.w) * rd.w);
        *(uint4*)&As[ar * 32 + ah]     = make_uint4(q0, q1, q2, q3);
        *(uint4*)&As[ar * 32 + ah + 8] = make_uint4(q4, q5, q6, q7);
        __syncthreads();

        bf8_t af[4], bf[4];
#pragma unroll
        for (int m = 0; m < 4; ++m)
            af[m] = *(const bf8_t*)&As[(wr * 64 + m * 16 + l15) * 32 + kg * 8];
#pragma unroll
        for (int n = 0; n < 4; ++n)
            bf[n] = *(const bf8_t*)&Bs[(wc * 64 + n * 16 + l15) * 32 + kg * 8];
#pragma unroll
        for (int m = 0; m < 4; ++m)
#pragma unroll
            for (int n = 0; n < 4; ++n)
                acc[m][n] = __builtin_amdgcn_mfma_f32_16x16x32_bf16(af[m], bf[n], acc[m][n], 0, 0, 0);
        __syncthreads();
    }

    const int orow = wr * 64 + (l >> 4) * 4;
    const int ocol = wc * 64 + l15;
#pragma unroll
    for (int m = 0; m < 4; ++m)
#pragma unroll
        for (int n = 0; n < 4; ++n)
#pragma unroll
            for (int r = 0; r < 4; ++r)
                C[(long)(m0 + orow + m * 16 + r) * D_ + (n0 + ocol + n * 16)] = acc[m][n][r];
}

__global__ __launch_bounds__(256)
void tr2bf_f(const float* __restrict__ src, long sSz, int ldS,
             unsigned short* __restrict__ dst, long sDz, int ldD)
{
    __shared__ unsigned short T[64][65];
    const int t = threadIdx.x;
    const int rr = t >> 2, cc = (t & 3) * 16;
    const int r0 = blockIdx.x * 64, c0 = blockIdx.y * 64, z = blockIdx.z;
    const float* S = src + (long)z * sSz + (long)(r0 + rr) * ldS + c0 + cc;
    const float4 a = *(const float4*)(S);
    const float4 b = *(const float4*)(S + 4);
    const float4 c = *(const float4*)(S + 8);
    const float4 d = *(const float4*)(S + 12);
    unsigned short* Tr = &T[rr][cc];
    Tr[0] = f2bf(a.x); Tr[1] = f2bf(a.y); Tr[2]  = f2bf(a.z); Tr[3]  = f2bf(a.w);
    Tr[4] = f2bf(b.x); Tr[5] = f2bf(b.y); Tr[6]  = f2bf(b.z); Tr[7]  = f2bf(b.w);
    Tr[8] = f2bf(c.x); Tr[9] = f2bf(c.y); Tr[10] = f2bf(c.z); Tr[11] = f2bf(c.w);
    Tr[12] = f2bf(d.x); Tr[13] = f2bf(d.y); Tr[14] = f2bf(d.z); Tr[15] = f2bf(d.w);
    __syncthreads();
    unsigned short v[16];
#pragma unroll
    for (int j = 0; j < 16; ++j) v[j] = T[cc + j][rr];
    unsigned q[8];
#pragma unroll
    for (int j = 0; j < 8; ++j) q[j] = (unsigned)v[2 * j] | ((unsigned)v[2 * j + 1] << 16);
    unsigned short* Dp = dst + (long)z * sDz + (long)(c0 + rr) * ldD + r0 + cc;
    *(uint4*)Dp       = make_uint4(q[0], q[1], q[2], q[3]);
    *(uint4*)(Dp + 8) = make_uint4(q[4], q[5], q[6], q[7]);
}

__global__ __launch_bounds__(256)
void tr2bf_h(const unsigned short* __restrict__ src, long sSz, int ldS,
             unsigned short* __restrict__ dst, long sDz, int ldD)
{
    __shared__ unsigned short T[64][65];
    const int t = threadIdx.x;
    const int rr = t >> 2, cc = (t & 3) * 16;
    const int r0 = blockIdx.x * 64, c0 = blockIdx.y * 64, z = blockIdx.z;
    const unsigned short* S = src + (long)z * sSz + (long)(r0 + rr) * ldS + c0 + cc;
    const uint4 qa = *(const uint4*)(S);
    const uint4 qb = *(const uint4*)(S + 8);
    unsigned short* Tr = &T[rr][cc];
    Tr[0]  = qa.x & 0xFFFF; Tr[1]  = qa.x >> 16; Tr[2]  = qa.y & 0xFFFF; Tr[3]  = qa.y >> 16;
    Tr[4]  = qa.z & 0xFFFF; Tr[5]  = qa.z >> 16; Tr[6]  = qa.w & 0xFFFF; Tr[7]  = qa.w >> 16;
    Tr[8]  = qb.x & 0xFFFF; Tr[9]  = qb.x >> 16; Tr[10] = qb.y & 0xFFFF; Tr[11] = qb.y >> 16;
    Tr[12] = qb.z & 0xFFFF; Tr[13] = qb.z >> 16; Tr[14] = qb.w & 0xFFFF; Tr[15] = qb.w >> 16;
    __syncthreads();
    unsigned short v[16];
#pragma unroll
    for (int j = 0; j < 16; ++j) v[j] = T[cc + j][rr];
    unsigned q[8];
#pragma unroll
    for (int j = 0; j < 8; ++j) q[j] = (unsigned)v[2 * j] | ((unsigned)v[2 * j + 1] << 16);
    unsigned short* Dp = dst + (long)z * sDz + (long)(c0 + rr) * ldD + r0 + cc;
    *(uint4*)Dp       = make_uint4(q[0], q[1], q[2], q[3]);
    *(uint4*)(Dp + 8) = make_uint4(q[4], q[5], q[6], q[7]);
}

__global__ __launch_bounds__(256)
void cvt_bf(const float* __restrict__ src, unsigned short* __restrict__ dst, long n)
{
    const long i = ((long)blockIdx.x * 256 + threadIdx.x) * 8;
    if (i >= n) return;
    const float4 a = *(const float4*)(src + i);
    const float4 b = *(const float4*)(src + i + 4);
    *(uint4*)(dst + i) = make_uint4(pk2(a.x, a.y), pk2(a.z, a.w), pk2(b.x, b.y), pk2(b.z, b.w));
}

// ---------------------------------------------------------------------------
extern "C" void kernel_launch(void* const* d_in, const int* in_sizes, int n_in,
                              void* d_out, int out_size, void* d_ws, size_t ws_size,
                              hipStream_t stream)
{
    (void)in_sizes; (void)n_in; (void)out_size;

    const float* V   = (const float*)d_in[0];
    const float* L   = (const float*)d_in[1];
    const float* w1V = (const float*)d_in[4];
    const float* b1V = (const float*)d_in[5];
    const float* w2V = (const float*)d_in[6];
    const float* b2V = (const float*)d_in[7];
    const float* w1L = (const float*)d_in[8];
    const float* b1L = (const float*)d_in[9];
    const float* w2L = (const float*)d_in[10];
    const float* b2L = (const float*)d_in[11];

    float* outA = (float*)d_out;                      // [B, NV, KTOT]
    float* outV = outA + (size_t)B_ * NV_ * KTOT;     // [B, NV, D]

    unsigned short* w1Vt = (unsigned short*)d_ws;                 // [H][D]
    unsigned short* w2Vt = w1Vt + (size_t)H_ * D_;                // [D][H]
    unsigned short* w1Lt = w2Vt + (size_t)D_ * H_;
    unsigned short* w2Lt = w1Lt + (size_t)H_ * D_;
    unsigned short* pool = w2Lt + (size_t)D_ * H_;

    // per-batch pool: Vb, Lb, hid, fCat=[fLL;fLV], KCat=[fLL;fV], KVt
    const size_t perb_us = (size_t)NV_ * D_ + (size_t)NL_ * D_ + (size_t)NV_ * H_ +
                           3ul * KTOT * D_;
    const size_t perb_bytes = perb_us * 2 + 2 * (size_t)KTOT * sizeof(float);
    const size_t persist_bytes = (size_t)4 * H_ * D_ * 2;
    const size_t avail = (ws_size > persist_bytes + 256) ? ws_size - persist_bytes - 256 : 0;
    int bc = (int)(avail / perb_bytes);
    if (bc > B_) bc = B_;
    if (bc < 1)  bc = 1;

    unsigned short* Vb   = pool;
    unsigned short* Lb   = Vb   + (size_t)bc * NV_ * D_;
    unsigned short* hid  = Lb   + (size_t)bc * NL_ * D_;
    unsigned short* fCat = hid  + (size_t)bc * NV_ * H_;   // [bc][768][D]
    unsigned short* KCat = fCat + (size_t)bc * KTOT * D_;  // [bc][768][D]
    unsigned short* KVt  = KCat + (size_t)bc * KTOT * D_;  // [bc][D][768]
    float* Mst = (float*)(KVt + (size_t)bc * D_ * KTOT);
    float* RS  = Mst + (size_t)bc * KTOT;

    const dim3 blk(256);
    const dim3 blk5(512);

    {
        auto* f0 = gemm256<0>;
        auto* f1 = gemm256<1>;
        auto* f2 = gemm256<2>;
        hipFuncSetAttribute((const void*)f0, hipFuncAttributeMaxDynamicSharedMemorySize, 65536);
        hipFuncSetAttribute((const void*)f1, hipFuncAttributeMaxDynamicSharedMemorySize, 65536);
        hipFuncSetAttribute((const void*)f2, hipFuncAttributeMaxDynamicSharedMemorySize, 65536);
    }

    tr2bf_f<<<dim3(D_ / 64, H_ / 64, 1), blk, 0, stream>>>(w1V, 0, H_, w1Vt, 0, D_);
    tr2bf_f<<<dim3(H_ / 64, D_ / 64, 1), blk, 0, stream>>>(w2V, 0, D_, w2Vt, 0, H_);
    tr2bf_f<<<dim3(D_ / 64, H_ / 64, 1), blk, 0, stream>>>(w1L, 0, H_, w1Lt, 0, D_);
    tr2bf_f<<<dim3(H_ / 64, D_ / 64, 1), blk, 0, stream>>>(w2L, 0, D_, w2Lt, 0, H_);

    for (int b0 = 0; b0 < B_; b0 += bc) {
        const int cur = (B_ - b0 < bc) ? (B_ - b0) : bc;

        cvt_bf<<<dim3(cur * NV_ * D_ / 2048), blk, 0, stream>>>(
            V + (size_t)b0 * NV_ * D_, Vb, (long)cur * NV_ * D_);
        cvt_bf<<<dim3(cur * NL_ * D_ / 2048), blk, 0, stream>>>(
            L + (size_t)b0 * NL_ * D_, Lb, (long)cur * NL_ * D_);

        #define G256(M, N) dim3((unsigned)(((N) / 256) * ((M) / 256) * cur)), blk5, 65536, stream
        #define P256(M, N) (N) / 256, (((N) / 256) * ((M) / 256)), \
                           ((((N) / 256) * ((M) / 256)) % 8 == 0 ? (((N) / 256) * ((M) / 256)) / 8 : 0)

        // FFN_V(V): Vb -> hid -> fV (KCat rows 256..767)
        gemm256<0><<<G256(NV_, H_)>>>(Vb, (long)NV_ * D_, D_, w1Vt, 0, D_, b1V, 0.f,
                                      hid, nullptr, (long)NV_ * H_, H_, D_, P256(NV_, H_));
        gemm256<1><<<G256(NV_, D_)>>>(hid, (long)NV_ * H_, H_, w2Vt, 0, H_, b2V, 0.f,
                                      KCat + (size_t)NL_ * D_, nullptr,
                                      (long)KTOT * D_, D_, H_, P256(NV_, D_));
        // FFN_L(L): Lb -> hid -> fLL (dual-store: fCat rows 0..255 AND KCat rows 0..255)
        gemm256<0><<<G256(NL_, H_)>>>(Lb, (long)NL_ * D_, D_, w1Lt, 0, D_, b1L, 0.f,
                                      hid, nullptr, (long)NV_ * H_, H_, D_, P256(NL_, H_));
        gemm256<1><<<G256(NL_, D_)>>>(hid, (long)NV_ * H_, H_, w2Lt, 0, H_, b2L, 0.f,
                                      fCat, KCat, (long)KTOT * D_, D_, H_, P256(NL_, D_));
        // FFN_L(V): Vb -> hid -> fLV (fCat rows 256..767)
        gemm256<0><<<G256(NV_, H_)>>>(Vb, (long)NV_ * D_, D_, w1Lt, 0, D_, b1L, 0.f,
                                      hid, nullptr, (long)NV_ * H_, H_, D_, P256(NV_, H_));
        gemm256<1><<<G256(NV_, D_)>>>(hid, (long)NV_ * H_, H_, w2Lt, 0, H_, b2L, 0.f,
                                      fCat + (size_t)NL_ * D_, nullptr,
                                      (long)KTOT * D_, D_, H_, P256(NV_, D_));

        // A = (fV @ fCat^T) * scale -> outA  (one 256-tile GEMM, N=768)
        gemm256<2><<<G256(NV_, KTOT)>>>(KCat + (size_t)NL_ * D_, (long)KTOT * D_, D_,
                                        fCat, (long)KTOT * D_, D_, nullptr, SCALE_,
                                        outA + (size_t)b0 * NV_ * KTOT, nullptr,
                                        (long)NV_ * KTOT, KTOT, D_, P256(NV_, KTOT));
        #undef G256
        #undef P256

        // KVt = KCat^T  (bf16 [D][768])
        tr2bf_h<<<dim3(KTOT / 64, D_ / 64, cur), blk, 0, stream>>>(
            KCat, (long)KTOT * D_, D_, KVt, (long)D_ * KTOT, KTOT);

        col_stats<<<dim3(KTOT / 64, cur), blk, 0, stream>>>(
            outA + (size_t)b0 * NV_ * KTOT, Mst, RS);

        attn_mfma<<<dim3((unsigned)((D_ / 128) * (NV_ / 128) * cur)), blk, 0, stream>>>(
            outA + (size_t)b0 * NV_ * KTOT, KVt, Mst, RS,
            outV + (size_t)b0 * NV_ * D_,
            D_ / 128, (D_ / 128) * (NV_ / 128) / 8);
    }
}

// Round 10
// 906.977 us; speedup vs baseline: 9.2171x; 9.2171x over previous
//
#include <hip/hip_runtime.h>
#include <stdint.h>

#define B_   32
#define NV_  512
#define NL_  256
#define D_   1024
#define H_   4096
#define KTOT 768
#define SCALE_ 0.03125f   // 1/sqrt(1024)

typedef __attribute__((ext_vector_type(8))) __bf16 bf8_t;
typedef __attribute__((ext_vector_type(4))) float f32x4;

__device__ __forceinline__ unsigned short f2bf(float f) {
    unsigned u = __float_as_uint(f);
    u += 0x7FFFu + ((u >> 16) & 1u);       // round-to-nearest-even
    return (unsigned short)(u >> 16);
}
__device__ __forceinline__ unsigned pk2(float lo, float hi) {
    return (unsigned)f2bf(lo) | ((unsigned)f2bf(hi) << 16);
}

// async global->LDS, 16B per lane. LDS dest = wave-uniform base + lane*16.
__device__ __forceinline__ void gl_lds16(const void* g, const void* lds) {
    __builtin_amdgcn_global_load_lds(
        (const __attribute__((address_space(1))) unsigned int*)(uintptr_t)g,
        (__attribute__((address_space(3))) unsigned int*)(unsigned)(uintptr_t)lds,
        16, 0, 0);
}

#define SBAR() asm volatile("s_barrier" ::: "memory")
#define VMC4() asm volatile("s_waitcnt vmcnt(4)" ::: "memory")
#define VMC0() asm volatile("s_waitcnt vmcnt(0)" ::: "memory")
#define LGK0() asm volatile("s_waitcnt lgkmcnt(0)" ::: "memory")

// ===========================================================================
// 256x256 bf16 MFMA GEMM — round-7 "2-stretch" schedule (best measured:
// 139 us / ~990 TF on FFN shapes) + round-8 epilogue options.
// 512 thr = 8 waves (2Mx4N); per wave 128x64; BK=64; LDS 128 KiB dbuf,
// XOR-swizzled (T2); staged via inverse-swizzled global source (rule #21).
// NO second __launch_bounds__ arg: (512,4) capped regs -> scratch (round 9).
//
// Per K-tile: stage A-halves(t+1); [read a1,b1] 32 MFMA; LGK0+SBAR(A);
//             stage B-halves(t+2); VMC4+SBAR(B); [pre-read t+1 q0] 32 MFMA;
//             SBAR(C).  Ledger: at VMC4 12 outstanding -> drain to 4 = t+1
// fully resident, t+2 B-halves in flight.
// EPI: 0 relu(acc+bias)->bf16 ; 1 acc+bias->bf16 (+optional C2p dual-store);
//      2 acc*scale -> f32 direct.
// ===========================================================================
template<int EPI>
__global__ __launch_bounds__(512, 1)
void gemm256(const unsigned short* __restrict__ Ab, long sAz, int lda,
             const unsigned short* __restrict__ Bb, long sBz, int ldb,
             const float* __restrict__ bias, float scale,
             void* __restrict__ Cp, unsigned short* __restrict__ C2p,
             long sCz, int ldc, int K,
             int nx, int ntile, int tpc)
{
    extern __shared__ unsigned char lds[];
    unsigned char* const ldsA = lds;            // (buf*2+half)*16384
    unsigned char* const ldsB = lds + 65536;

    const int tid = threadIdx.x;
    const int w = tid >> 6, l = tid & 63;
    const int wr = w >> 2, wc = w & 3;          // 2 x 4 wave grid
    const int lrow = l & 15;
    const int kg = l >> 4;

    int t_, z;
    {
        const int bid = blockIdx.x;
        if (tpc > 0) { const int r = bid >> 3, c = bid & 7; z = r / tpc; t_ = c * tpc + r % tpc; }
        else         { z = bid / ntile; t_ = bid - z * ntile; }
    }
    const int n0 = (t_ % nx) * 256, m0 = (t_ / nx) * 256;

    const unsigned short* A  = Ab + (long)z * sAz;
    const unsigned short* Bg = Bb + (long)z * sBz;

    const int srow = tid >> 3;                               // row 0..63 in 64-row block
    const int scol = ((tid & 7) * 8) ^ ((srow & 7) << 3);    // inverse-swizzled src col
    const int ntk = K >> 6;                                  // # K-tiles (even)

    const int cs0 = (((l >> 4) * 16)) ^ ((l & 7) << 4);
    const int cs1 = (64 + ((l >> 4) * 16)) ^ ((l & 7) << 4);

    const unsigned short* const sp0 = Bg + (long)(n0 +   0 + srow) * ldb + scol;
    const unsigned short* const sp1 = Bg + (long)(n0 + 128 + srow) * ldb + scol;
    const unsigned short* const sp2 = A  + (long)(m0 +   0 + srow) * lda + scol;
    const unsigned short* const sp3 = A  + (long)(m0 + 128 + srow) * lda + scol;
    const long stB = (long)64 * ldb, stA = (long)64 * lda;

    f32x4 acc[8][4];
#pragma unroll
    for (int i = 0; i < 8; ++i)
#pragma unroll
        for (int j = 0; j < 4; ++j) acc[i][j] = (f32x4){0.f, 0.f, 0.f, 0.f};

#define STG(tau, part) do {                                                   \
        const int buf_ = (tau) & 1;                                           \
        const int kt_ = ((tau) < ntk ? (tau) : ntk - 1);                      \
        if ((part) < 2) {                                                     \
            const unsigned short* s_ = ((part) == 0 ? sp0 : sp1) + (long)kt_ * 64; \
            unsigned char* d_ = ldsB + (buf_ * 2 + (part)) * 16384 + w * 1024;\
            gl_lds16(s_, d_); gl_lds16(s_ + stB, d_ + 8192);                  \
        } else {                                                              \
            const unsigned short* s_ = ((part) == 2 ? sp2 : sp3) + (long)kt_ * 64; \
            unsigned char* d_ = ldsA + (buf_ * 2 + (part) - 2) * 16384 + w * 1024; \
            gl_lds16(s_, d_); gl_lds16(s_ + stA, d_ + 8192);                  \
        } } while (0)

    auto rdA = [&](int buf, int mf, int cs) -> bf8_t {
        return *(const bf8_t*)(ldsA + (buf * 2 + wr) * 16384 + (mf * 16 + lrow) * 128 + cs);
    };
    auto rdB = [&](int buf, int nf, int cs) -> bf8_t {
        return *(const bf8_t*)(ldsB + (buf * 2 + (wc >> 1)) * 16384 +
                               ((wc & 1) * 64 + nf * 16 + lrow) * 128 + cs);
    };

#define MQ(MO, NO, AREG, BREG)                                                \
    _Pragma("unroll")                                                         \
    for (int mf = 0; mf < 4; ++mf)                                            \
    _Pragma("unroll")                                                         \
        for (int nf = 0; nf < 2; ++nf) {                                      \
            acc[(MO)+mf][(NO)+nf] = __builtin_amdgcn_mfma_f32_16x16x32_bf16(  \
                AREG[mf][0], BREG[nf][0], acc[(MO)+mf][(NO)+nf], 0, 0, 0);    \
            acc[(MO)+mf][(NO)+nf] = __builtin_amdgcn_mfma_f32_16x16x32_bf16(  \
                AREG[mf][1], BREG[nf][1], acc[(MO)+mf][(NO)+nf], 0, 0, 0);    \
        }

    // ---- prologue: tile0 all parts + tile1 B halves; tile0 resident ----
    STG(0, 0); STG(0, 1); STG(0, 2); STG(0, 3);
    STG(1, 0); STG(1, 1);
    VMC4();
    SBAR();

    bf8_t a0A[4][2], b0A[2][2];     // even-tile pre-read set
    bf8_t a0B[4][2], b0B[2][2];     // odd-tile pre-read set
    bf8_t a1r[4][2], b1r[2][2];     // within-tile set

#pragma unroll
    for (int mf = 0; mf < 4; ++mf) { a0A[mf][0] = rdA(0, mf, cs0);
                                     a0A[mf][1] = rdA(0, mf, cs1); }
#pragma unroll
    for (int nf = 0; nf < 2; ++nf) { b0A[nf][0] = rdB(0, nf, cs0);
                                     b0A[nf][1] = rdB(0, nf, cs1); }

#define TILEX(BUF, A0C, B0C, A0N, B0N, TAU)                                   \
    STG((TAU) + 1, 2); STG((TAU) + 1, 3);                                     \
    __builtin_amdgcn_s_setprio(1);                                            \
    _Pragma("unroll")                                                         \
    for (int mf = 0; mf < 4; ++mf) { a1r[mf][0] = rdA(BUF, mf + 4, cs0);      \
                                     a1r[mf][1] = rdA(BUF, mf + 4, cs1); }    \
    _Pragma("unroll")                                                         \
    for (int nf = 0; nf < 2; ++nf) { b1r[nf][0] = rdB(BUF, nf + 2, cs0);      \
                                     b1r[nf][1] = rdB(BUF, nf + 2, cs1); }    \
    MQ(0, 0, A0C, B0C)                                                        \
    MQ(0, 2, A0C, b1r)                                                        \
    __builtin_amdgcn_s_setprio(0);                                            \
    LGK0();                                                                   \
    SBAR();                                   /* A: buf_t reads all done */   \
    STG((TAU) + 2, 0); STG((TAU) + 2, 1);                                     \
    VMC4();                                   /* tile TAU+1 resident */       \
    SBAR();                                   /* B */                         \
    __builtin_amdgcn_s_setprio(1);                                            \
    _Pragma("unroll")                                                         \
    for (int mf = 0; mf < 4; ++mf) { A0N[mf][0] = rdA((BUF) ^ 1, mf, cs0);    \
                                     A0N[mf][1] = rdA((BUF) ^ 1, mf, cs1); }  \
    _Pragma("unroll")                                                         \
    for (int nf = 0; nf < 2; ++nf) { B0N[nf][0] = rdB((BUF) ^ 1, nf, cs0);    \
                                     B0N[nf][1] = rdB((BUF) ^ 1, nf, cs1); }  \
    MQ(4, 0, a1r, B0C)                                                        \
    MQ(4, 2, a1r, b1r)                                                        \
    __builtin_amdgcn_s_setprio(0);                                            \
    SBAR();                                   /* C */

    for (int t = 0; t < ntk; t += 2) {
        TILEX(0, a0A, b0A, a0B, b0B, t)
        TILEX(1, a0B, b0B, a0A, b0A, t + 1)
    }
#undef TILEX
#undef MQ
#undef STG

    VMC0();   // drain garbage tail stages
    SBAR();   // all waves drained -> LDS safe to repurpose

    if (EPI == 2) {
        float* C = (float*)Cp + (long)z * sCz;
#pragma unroll
        for (int mf = 0; mf < 8; ++mf)
#pragma unroll
            for (int nf = 0; nf < 4; ++nf)
#pragma unroll
                for (int r = 0; r < 4; ++r)
                    C[(long)(m0 + wr * 128 + mf * 16 + kg * 4 + r) * ldc +
                      (n0 + wc * 64 + nf * 16 + lrow)] = acc[mf][nf][r] * scale;
        return;
    }

    // ---- bf16 epilogue: per-wave LDS repack -> full-cacheline stores ----
    unsigned short* C  = (unsigned short*)Cp + (long)z * sCz;
    unsigned short* C2 = C2p ? (C2p + (long)z * sCz) : nullptr;
    unsigned char* const scr = lds + w * 16384;   // 16 KiB per-wave scratch

    float bv[4];
#pragma unroll
    for (int nf = 0; nf < 4; ++nf) bv[nf] = bias[n0 + wc * 64 + nf * 16 + lrow];

#pragma unroll
    for (int p = 0; p < 2; ++p) {
#pragma unroll
        for (int mf = 0; mf < 4; ++mf)
#pragma unroll
            for (int nf = 0; nf < 4; ++nf)
#pragma unroll
                for (int r = 0; r < 4; ++r) {
                    float v = acc[4 * p + mf][nf][r] + bv[nf];
                    if (EPI == 0) v = fmaxf(v, 0.f);
                    *(unsigned short*)(scr + (mf * 16 + kg * 4 + r) * 136 +
                                       (nf * 16 + lrow) * 2) = f2bf(v);
                }
#pragma unroll
        for (int it = 0; it < 8; ++it) {
            const int rr = it * 8 + (l >> 3);
            const uint4 q = *(const uint4*)(scr + rr * 136 + (l & 7) * 16);
            const long off = (long)(m0 + wr * 128 + p * 64 + rr) * ldc +
                             (n0 + wc * 64 + (l & 7) * 8);
            *(uint4*)(C + off) = q;
            if (C2) *(uint4*)(C2 + off) = q;
        }
    }
}

// ===========================================================================
// attn + helpers (unchanged).
// ===========================================================================
__device__ __forceinline__ void supertile(int nx, int tpc, int& n0, int& m0, int& z)
{
    const int bid = blockIdx.x;
    const int r = bid >> 3, c = bid & 7;
    z = r / tpc;
    const int t = c * tpc + (r % tpc);
    n0 = (t % nx) * 128;
    m0 = (t / nx) * 128;
}

__global__ __launch_bounds__(256)
void col_stats(const float* __restrict__ A, float* __restrict__ Mst, float* __restrict__ RS)
{
    __shared__ float red[4][64];
    const int t = threadIdx.x;
    const int kk = t & 63, ng = t >> 6;
    const int k = blockIdx.x * 64 + kk;
    const int z = blockIdx.y;
    const float* base = A + (long)z * NV_ * KTOT + k;
    float m = -3.0e38f;
    for (int n = ng * 128; n < ng * 128 + 128; ++n) m = fmaxf(m, base[(long)n * KTOT]);
    red[ng][kk] = m;
    __syncthreads();
    m = fmaxf(fmaxf(red[0][kk], red[1][kk]), fmaxf(red[2][kk], red[3][kk]));
    float s = 0.f;
    for (int n = ng * 128; n < ng * 128 + 128; ++n) s += __expf(base[(long)n * KTOT] - m);
    __syncthreads();
    red[ng][kk] = s;
    __syncthreads();
    if (ng == 0) {
        s = red[0][kk] + red[1][kk] + red[2][kk] + red[3][kk];
        Mst[(long)z * KTOT + k] = m;
        RS[(long)z * KTOT + k]  = 1.f / s;
    }
}

__global__ __launch_bounds__(256)
void attn_mfma(const float* __restrict__ Ap, const unsigned short* __restrict__ KVt,
               const float* __restrict__ Mstp, const float* __restrict__ RSp,
               float* __restrict__ Cp, int nx, int tpc)
{
    __shared__ unsigned short As[128 * 32];
    __shared__ unsigned short Bs[128 * 32];

    const int tid = threadIdx.x;
    const int w = tid >> 6, l = tid & 63;
    const int wr = w >> 1, wc = w & 1;
    const int l15 = l & 15, kg = l >> 4;
    const int srow = l >> 2, scol = (l & 3) * 8;
    int n0, m0, z;
    supertile(nx, tpc, n0, m0, z);

    const float* A = Ap + (long)z * NV_ * KTOT;
    const unsigned short* Bg = KVt + (long)z * D_ * KTOT;
    const float* Mz = Mstp + (long)z * KTOT;
    const float* Rz = RSp  + (long)z * KTOT;
    float* C = Cp + (long)z * NV_ * D_;

    const int ar = tid >> 1;
    const int ah = (tid & 1) * 16;

    f32x4 acc[4][4];
#pragma unroll
    for (int m = 0; m < 4; ++m)
#pragma unroll
        for (int n = 0; n < 4; ++n) acc[m][n] = (f32x4){0.f, 0.f, 0.f, 0.f};

    for (int k0 = 0; k0 < KTOT; k0 += 32) {
#pragma unroll
        for (int i = 0; i < 2; ++i) {
            const int g = i * 4 + w;
            gl_lds16(Bg + (long)(n0 + g * 16 + srow) * KTOT + (k0 + scol), &Bs[g * 512]);
        }
        const float* arow = A + (long)(m0 + ar) * KTOT + k0 + ah;
        const float4 x0 = *(const float4*)(arow);
        const float4 x1 = *(const float4*)(arow + 4);
        const float4 x2 = *(const float4*)(arow + 8);
        const float4 x3 = *(const float4*)(arow + 12);
        const float4 ma = *(const float4*)(Mz + k0 + ah);
        const float4 mb = *(const float4*)(Mz + k0 + ah + 4);
        const float4 mc = *(const float4*)(Mz + k0 + ah + 8);
        const float4 md = *(const float4*)(Mz + k0 + ah + 12);
        const float4 ra = *(const float4*)(Rz + k0 + ah);
        const float4 rb = *(const float4*)(Rz + k0 + ah + 4);
        const float4 rc = *(const float4*)(Rz + k0 + ah + 8);
        const float4 rd = *(const float4*)(Rz + k0 + ah + 12);
        const unsigned q0 = pk2(__expf(x0.x - ma.x) * ra.x, __expf(x0.y - ma.y) * ra.y);
        const unsigned q1 = pk2(__expf(x0.z - ma.z) * ra.z, __expf(x0.w - ma.w) * ra.w);
        const unsigned q2 = pk2(__expf(x1.x - mb.x) * rb.x, __expf(x1.y - mb.y) * rb.y);
        const unsigned q3 = pk2(__expf(x1.z - mb.z) * rb.z, __expf(x1.w - mb.w) * rb.w);
        const unsigned q4 = pk2(__expf(x2.x - mc.x) * rc.x, __expf(x2.y - mc.y) * rc.y);
        const unsigned q5 = pk2(__expf(x2.z - mc.z) * rc.z, __expf(x2.w - mc.w) * rc.w);
        const unsigned q6 = pk2(__expf(x3.x - md.x) * rd.x, __expf(x3.y - md.y) * rd.y);
        const unsigned q7 = pk2(__expf(x3.z - md.z) * rd.z, __expf(x3.w - md.w) * rd.w);
        *(uint4*)&As[ar * 32 + ah]     = make_uint4(q0, q1, q2, q3);
        *(uint4*)&As[ar * 32 + ah + 8] = make_uint4(q4, q5, q6, q7);
        __syncthreads();

        bf8_t af[4], bf[4];
#pragma unroll
        for (int m = 0; m < 4; ++m)
            af[m] = *(const bf8_t*)&As[(wr * 64 + m * 16 + l15) * 32 + kg * 8];
#pragma unroll
        for (int n = 0; n < 4; ++n)
            bf[n] = *(const bf8_t*)&Bs[(wc * 64 + n * 16 + l15) * 32 + kg * 8];
#pragma unroll
        for (int m = 0; m < 4; ++m)
#pragma unroll
            for (int n = 0; n < 4; ++n)
                acc[m][n] = __builtin_amdgcn_mfma_f32_16x16x32_bf16(af[m], bf[n], acc[m][n], 0, 0, 0);
        __syncthreads();
    }

    const int orow = wr * 64 + (l >> 4) * 4;
    const int ocol = wc * 64 + l15;
#pragma unroll
    for (int m = 0; m < 4; ++m)
#pragma unroll
        for (int n = 0; n < 4; ++n)
#pragma unroll
            for (int r = 0; r < 4; ++r)
                C[(long)(m0 + orow + m * 16 + r) * D_ + (n0 + ocol + n * 16)] = acc[m][n][r];
}

__global__ __launch_bounds__(256)
void tr2bf_f(const float* __restrict__ src, long sSz, int ldS,
             unsigned short* __restrict__ dst, long sDz, int ldD)
{
    __shared__ unsigned short T[64][65];
    const int t = threadIdx.x;
    const int rr = t >> 2, cc = (t & 3) * 16;
    const int r0 = blockIdx.x * 64, c0 = blockIdx.y * 64, z = blockIdx.z;
    const float* S = src + (long)z * sSz + (long)(r0 + rr) * ldS + c0 + cc;
    const float4 a = *(const float4*)(S);
    const float4 b = *(const float4*)(S + 4);
    const float4 c = *(const float4*)(S + 8);
    const float4 d = *(const float4*)(S + 12);
    unsigned short* Tr = &T[rr][cc];
    Tr[0] = f2bf(a.x); Tr[1] = f2bf(a.y); Tr[2]  = f2bf(a.z); Tr[3]  = f2bf(a.w);
    Tr[4] = f2bf(b.x); Tr[5] = f2bf(b.y); Tr[6]  = f2bf(b.z); Tr[7]  = f2bf(b.w);
    Tr[8] = f2bf(c.x); Tr[9] = f2bf(c.y); Tr[10] = f2bf(c.z); Tr[11] = f2bf(c.w);
    Tr[12] = f2bf(d.x); Tr[13] = f2bf(d.y); Tr[14] = f2bf(d.z); Tr[15] = f2bf(d.w);
    __syncthreads();
    unsigned short v[16];
#pragma unroll
    for (int j = 0; j < 16; ++j) v[j] = T[cc + j][rr];
    unsigned q[8];
#pragma unroll
    for (int j = 0; j < 8; ++j) q[j] = (unsigned)v[2 * j] | ((unsigned)v[2 * j + 1] << 16);
    unsigned short* Dp = dst + (long)z * sDz + (long)(c0 + rr) * ldD + r0 + cc;
    *(uint4*)Dp       = make_uint4(q[0], q[1], q[2], q[3]);
    *(uint4*)(Dp + 8) = make_uint4(q[4], q[5], q[6], q[7]);
}

__global__ __launch_bounds__(256)
void tr2bf_h(const unsigned short* __restrict__ src, long sSz, int ldS,
             unsigned short* __restrict__ dst, long sDz, int ldD)
{
    __shared__ unsigned short T[64][65];
    const int t = threadIdx.x;
    const int rr = t >> 2, cc = (t & 3) * 16;
    const int r0 = blockIdx.x * 64, c0 = blockIdx.y * 64, z = blockIdx.z;
    const unsigned short* S = src + (long)z * sSz + (long)(r0 + rr) * ldS + c0 + cc;
    const uint4 qa = *(const uint4*)(S);
    const uint4 qb = *(const uint4*)(S + 8);
    unsigned short* Tr = &T[rr][cc];
    Tr[0]  = qa.x & 0xFFFF; Tr[1]  = qa.x >> 16; Tr[2]  = qa.y & 0xFFFF; Tr[3]  = qa.y >> 16;
    Tr[4]  = qa.z & 0xFFFF; Tr[5]  = qa.z >> 16; Tr[6]  = qa.w & 0xFFFF; Tr[7]  = qa.w >> 16;
    Tr[8]  = qb.x & 0xFFFF; Tr[9]  = qb.x >> 16; Tr[10] = qb.y & 0xFFFF; Tr[11] = qb.y >> 16;
    Tr[12] = qb.z & 0xFFFF; Tr[13] = qb.z >> 16; Tr[14] = qb.w & 0xFFFF; Tr[15] = qb.w >> 16;
    __syncthreads();
    unsigned short v[16];
#pragma unroll
    for (int j = 0; j < 16; ++j) v[j] = T[cc + j][rr];
    unsigned q[8];
#pragma unroll
    for (int j = 0; j < 8; ++j) q[j] = (unsigned)v[2 * j] | ((unsigned)v[2 * j + 1] << 16);
    unsigned short* Dp = dst + (long)z * sDz + (long)(c0 + rr) * ldD + r0 + cc;
    *(uint4*)Dp       = make_uint4(q[0], q[1], q[2], q[3]);
    *(uint4*)(Dp + 8) = make_uint4(q[4], q[5], q[6], q[7]);
}

__global__ __launch_bounds__(256)
void cvt_bf(const float* __restrict__ src, unsigned short* __restrict__ dst, long n)
{
    const long i = ((long)blockIdx.x * 256 + threadIdx.x) * 8;
    if (i >= n) return;
    const float4 a = *(const float4*)(src + i);
    const float4 b = *(const float4*)(src + i + 4);
    *(uint4*)(dst + i) = make_uint4(pk2(a.x, a.y), pk2(a.z, a.w), pk2(b.x, b.y), pk2(b.z, b.w));
}

// ---------------------------------------------------------------------------
extern "C" void kernel_launch(void* const* d_in, const int* in_sizes, int n_in,
                              void* d_out, int out_size, void* d_ws, size_t ws_size,
                              hipStream_t stream)
{
    (void)in_sizes; (void)n_in; (void)out_size;

    const float* V   = (const float*)d_in[0];
    const float* L   = (const float*)d_in[1];
    const float* w1V = (const float*)d_in[4];
    const float* b1V = (const float*)d_in[5];
    const float* w2V = (const float*)d_in[6];
    const float* b2V = (const float*)d_in[7];
    const float* w1L = (const float*)d_in[8];
    const float* b1L = (const float*)d_in[9];
    const float* w2L = (const float*)d_in[10];
    const float* b2L = (const float*)d_in[11];

    float* outA = (float*)d_out;                      // [B, NV, KTOT]
    float* outV = outA + (size_t)B_ * NV_ * KTOT;     // [B, NV, D]

    unsigned short* w1Vt = (unsigned short*)d_ws;                 // [H][D]
    unsigned short* w2Vt = w1Vt + (size_t)H_ * D_;                // [D][H]
    unsigned short* w1Lt = w2Vt + (size_t)D_ * H_;
    unsigned short* w2Lt = w1Lt + (size_t)H_ * D_;
    unsigned short* pool = w2Lt + (size_t)D_ * H_;

    // per-batch pool: Vb, Lb, hid, fCat=[fLL;fLV], KCat=[fLL;fV], KVt
    const size_t perb_us = (size_t)NV_ * D_ + (size_t)NL_ * D_ + (size_t)NV_ * H_ +
                           3ul * KTOT * D_;
    const size_t perb_bytes = perb_us * 2 + 2 * (size_t)KTOT * sizeof(float);
    const size_t persist_bytes = (size_t)4 * H_ * D_ * 2;
    const size_t avail = (ws_size > persist_bytes + 256) ? ws_size - persist_bytes - 256 : 0;
    int bc = (int)(avail / perb_bytes);
    if (bc > B_) bc = B_;
    if (bc < 1)  bc = 1;

    unsigned short* Vb   = pool;
    unsigned short* Lb   = Vb   + (size_t)bc * NV_ * D_;
    unsigned short* hid  = Lb   + (size_t)bc * NL_ * D_;
    unsigned short* fCat = hid  + (size_t)bc * NV_ * H_;   // [bc][768][D]
    unsigned short* KCat = fCat + (size_t)bc * KTOT * D_;  // [bc][768][D]
    unsigned short* KVt  = KCat + (size_t)bc * KTOT * D_;  // [bc][D][768]
    float* Mst = (float*)(KVt + (size_t)bc * D_ * KTOT);
    float* RS  = Mst + (size_t)bc * KTOT;

    const dim3 blk(256);
    const dim3 blk5(512);

    {
        auto* f0 = gemm256<0>;
        auto* f1 = gemm256<1>;
        auto* f2 = gemm256<2>;
        hipFuncSetAttribute((const void*)f0, hipFuncAttributeMaxDynamicSharedMemorySize, 131072);
        hipFuncSetAttribute((const void*)f1, hipFuncAttributeMaxDynamicSharedMemorySize, 131072);
        hipFuncSetAttribute((const void*)f2, hipFuncAttributeMaxDynamicSharedMemorySize, 131072);
    }

    tr2bf_f<<<dim3(D_ / 64, H_ / 64, 1), blk, 0, stream>>>(w1V, 0, H_, w1Vt, 0, D_);
    tr2bf_f<<<dim3(H_ / 64, D_ / 64, 1), blk, 0, stream>>>(w2V, 0, D_, w2Vt, 0, H_);
    tr2bf_f<<<dim3(D_ / 64, H_ / 64, 1), blk, 0, stream>>>(w1L, 0, H_, w1Lt, 0, D_);
    tr2bf_f<<<dim3(H_ / 64, D_ / 64, 1), blk, 0, stream>>>(w2L, 0, D_, w2Lt, 0, H_);

    for (int b0 = 0; b0 < B_; b0 += bc) {
        const int cur = (B_ - b0 < bc) ? (B_ - b0) : bc;

        cvt_bf<<<dim3(cur * NV_ * D_ / 2048), blk, 0, stream>>>(
            V + (size_t)b0 * NV_ * D_, Vb, (long)cur * NV_ * D_);
        cvt_bf<<<dim3(cur * NL_ * D_ / 2048), blk, 0, stream>>>(
            L + (size_t)b0 * NL_ * D_, Lb, (long)cur * NL_ * D_);

        #define G256(M, N) dim3((unsigned)(((N) / 256) * ((M) / 256) * cur)), blk5, 131072, stream
        #define P256(M, N) (N) / 256, (((N) / 256) * ((M) / 256)), \
                           ((((N) / 256) * ((M) / 256)) % 8 == 0 ? (((N) / 256) * ((M) / 256)) / 8 : 0)

        // FFN_V(V): Vb -> hid -> fV (KCat rows 256..767)
        gemm256<0><<<G256(NV_, H_)>>>(Vb, (long)NV_ * D_, D_, w1Vt, 0, D_, b1V, 0.f,
                                      hid, nullptr, (long)NV_ * H_, H_, D_, P256(NV_, H_));
        gemm256<1><<<G256(NV_, D_)>>>(hid, (long)NV_ * H_, H_, w2Vt, 0, H_, b2V, 0.f,
                                      KCat + (size_t)NL_ * D_, nullptr,
                                      (long)KTOT * D_, D_, H_, P256(NV_, D_));
        // FFN_L(L): Lb -> hid -> fLL (dual-store: fCat rows 0..255 AND KCat rows 0..255)
        gemm256<0><<<G256(NL_, H_)>>>(Lb, (long)NL_ * D_, D_, w1Lt, 0, D_, b1L, 0.f,
                                      hid, nullptr, (long)NV_ * H_, H_, D_, P256(NL_, H_));
        gemm256<1><<<G256(NL_, D_)>>>(hid, (long)NV_ * H_, H_, w2Lt, 0, H_, b2L, 0.f,
                                      fCat, KCat, (long)KTOT * D_, D_, H_, P256(NL_, D_));
        // FFN_L(V): Vb -> hid -> fLV (fCat rows 256..767)
        gemm256<0><<<G256(NV_, H_)>>>(Vb, (long)NV_ * D_, D_, w1Lt, 0, D_, b1L, 0.f,
                                      hid, nullptr, (long)NV_ * H_, H_, D_, P256(NV_, H_));
        gemm256<1><<<G256(NV_, D_)>>>(hid, (long)NV_ * H_, H_, w2Lt, 0, H_, b2L, 0.f,
                                      fCat + (size_t)NL_ * D_, nullptr,
                                      (long)KTOT * D_, D_, H_, P256(NV_, D_));

        // A = (fV @ fCat^T) * scale -> outA  (one 256-tile GEMM, N=768)
        gemm256<2><<<G256(NV_, KTOT)>>>(KCat + (size_t)NL_ * D_, (long)KTOT * D_, D_,
                                        fCat, (long)KTOT * D_, D_, nullptr, SCALE_,
                                        outA + (size_t)b0 * NV_ * KTOT, nullptr,
                                        (long)NV_ * KTOT, KTOT, D_, P256(NV_, KTOT));
        #undef G256
        #undef P256

        // KVt = KCat^T  (bf16 [D][768])
        tr2bf_h<<<dim3(KTOT / 64, D_ / 64, cur), blk, 0, stream>>>(
            KCat, (long)KTOT * D_, D_, KVt, (long)D_ * KTOT, KTOT);

        col_stats<<<dim3(KTOT / 64, cur), blk, 0, stream>>>(
            outA + (size_t)b0 * NV_ * KTOT, Mst, RS);

        attn_mfma<<<dim3((unsigned)((D_ / 128) * (NV_ / 128) * cur)), blk, 0, stream>>>(
            outA + (size_t)b0 * NV_ * KTOT, KVt, Mst, RS,
            outV + (size_t)b0 * NV_ * D_,
            D_ / 128, (D_ / 128) * (NV_ / 128) / 8);
    }
}